// Round 9
// baseline (23.657 us; speedup 1.0000x reference)
//
#include <hip/hip_runtime.h>

#define KH 512
#define KW 512
#define TW 2

typedef float f32x2 __attribute__((ext_vector_type(2)));

__global__ __launch_bounds__(256)
void TrainableFilter_75118978007282_kernel(const float* __restrict__ x,
                                           const float* __restrict__ wsp,
                                           float* __restrict__ out) {
    // block (64,4); each thread computes TW=2 adjacent pixels of one row.
    // Window per row = cols [w0-2, w0+3], three 8B-aligned f32x2 loads.
    // Minimal live state -> low VGPR -> 8 waves/SIMD natural occupancy.
    const int tx = threadIdx.x;
    const int w0 = blockIdx.x * (64 * TW) + tx * TW;
    const int h  = blockIdx.y * 4 + threadIdx.y;
    const int plane = blockIdx.z;
    const float* __restrict__ xp = x + (size_t)plane * KH * KW;

    const bool left  = (w0 == 0);
    const bool right = (w0 == KW - TW);
    // clamped segment bases; reflected cols land in correct slots by construction
    const int bA = left  ? 0        : (w0 - 2);
    const int bC = right ? (KW - 2) : (w0 + 2);

    // center tap (ki=2,j=2): d==0, g==wsp[12] -> folded into den init
    const float w12 = wsp[12];
    f32x2 num = {0.f, 0.f};
    f32x2 den = {w12, w12};
    f32x2 c;

    const float NC2 = -0.72134752f;  // -0.5*log2(e): exp(-0.5 d^2)=exp2(d^2*NC2)

    // row order {2,0,1,3,4}: row 2 first so centers come from its window
    const int order[5] = {2, 0, 1, 3, 4};
#pragma unroll
    for (int rr = 0; rr < 5; ++rr) {
        const int ki = order[rr];
        int hh = h + ki - 2;
        hh = (hh < 0) ? -hh : hh;
        hh = (hh >= KH) ? (2 * KH - 2 - hh) : hh;
        const float* __restrict__ rp = xp + (size_t)hh * KW;

        const f32x2 sA = *reinterpret_cast<const f32x2*>(rp + bA);
        const f32x2 sB = *reinterpret_cast<const f32x2*>(rp + w0);
        const f32x2 sC = *reinterpret_cast<const f32x2*>(rp + bC);
        // win[i] = col w0-2+i
        float win[6] = { sA.x, sA.y, sB.x, sB.y, sC.x, sC.y };
        // reflect fixups (2 selects; other edge cols land correct via clamp):
        //  left  (w0==0,  bA->0):    win[0] wants col -2 -> 2 = win[4]; win[1] wants -1 -> 1 (ok)
        //  right (w0==510, bC->510): win[4] wants 512 -> 510 (ok);      win[5] wants 513 -> 509 = win[1]
        win[0] = left  ? win[4] : win[0];
        win[5] = right ? win[1] : win[5];

        if (ki == 2) { c.x = win[2]; c.y = win[3]; }

#pragma unroll
        for (int j = 0; j < 5; ++j) {
            if (ki == 2 && j == 2) continue;    // folded into den init
            const float wkv = wsp[ki * 5 + j];  // uniform -> SGPR
            const f32x2 p = {win[j], win[j + 1]};
            const f32x2 d = p - c;
            const f32x2 t = d * NC2;
            const f32x2 a = d * t;              // d^2 * NC2 (<=0)
            f32x2 e;
            e.x = __builtin_amdgcn_exp2f(a.x);
            e.y = __builtin_amdgcn_exp2f(a.y);
            const f32x2 g = e * wkv;
            num = num + g * d;
            den = den + g;
        }
    }

    f32x2 o;
    o.x = c.x + __fdividef(num.x, den.x);
    o.y = c.y + __fdividef(num.y, den.y);
    *reinterpret_cast<f32x2*>(out + (size_t)plane * KH * KW + (size_t)h * KW + w0) = o;
}

extern "C" void kernel_launch(void* const* d_in, const int* in_sizes, int n_in,
                              void* d_out, int out_size, void* d_ws, size_t ws_size,
                              hipStream_t stream) {
    const float* x   = (const float*)d_in[0];
    const float* wsp = (const float*)d_in[1];
    float* out = (float*)d_out;

    const int planes = out_size / (KH * KW);  // B*C = 12

    dim3 block(64, 4, 1);
    dim3 grid(KW / (64 * TW), KH / 4, planes);
    TrainableFilter_75118978007282_kernel<<<grid, block, 0, stream>>>(x, wsp, out);
}

// Round 10
// 19.564 us; speedup vs baseline: 1.2092x; 1.2092x over previous
//
#include <hip/hip_runtime.h>

#define KH 512
#define KW 512
#define TW 4

typedef float f32x2 __attribute__((ext_vector_type(2)));

__global__ __launch_bounds__(256)
void TrainableFilter_75118978007282_kernel(const float* __restrict__ x,
                                           const float* __restrict__ wsp,
                                           float* __restrict__ out) {
    // block (64,4); each thread computes TW=4 adjacent pixels of one row,
    // two f32x2 pairs -> v_pk_*_f32 packed math.
    // exp(-0.5 d^2) via Schraudolph: bitcast((int)(d^2*A + C)),
    // A = -0.5*log2(e)*2^23, C = 126.94269504*2^23  (rel err <= ~3.1%,
    // common-mode cancels in num/den ratio).
    const int tx = threadIdx.x;
    const int w0 = blockIdx.x * (64 * TW) + tx * TW;
    const int h  = blockIdx.y * 4 + threadIdx.y;
    const int plane = blockIdx.z;
    const float* __restrict__ xp = x + (size_t)plane * KH * KW;

    const bool left  = (w0 == 0);
    const bool right = (w0 == KW - TW);
    const int b0 = left ? 0 : (w0 - 4);
    const int b2 = right ? (KW - 4) : (w0 + 4);

    const float4 cv = *reinterpret_cast<const float4*>(xp + (size_t)h * KW + w0);
    const f32x2 c01 = {cv.x, cv.y};
    const f32x2 c23 = {cv.z, cv.w};

    // center tap (ki=2,j=2): d==0 -> g==wsp[12] exactly; fold into den init
    // (exact, not Schraudolph'd: avoids approx error on the heaviest tap)
    const float w12 = wsp[12];
    f32x2 num01 = {0.f, 0.f}, num23 = {0.f, 0.f};
    f32x2 den01 = {w12, w12}, den23 = {w12, w12};

    const float A = -0.72134752f * 8388608.0f;   // -0.5*log2(e) * 2^23
    const float C = 126.94269504f * 8388608.0f;  // Schraudolph bias * 2^23
    const f32x2 Cv = {C, C};

#pragma unroll
    for (int ki = 0; ki < 5; ++ki) {
        int hh = h + ki - 2;
        hh = (hh < 0) ? -hh : hh;
        hh = (hh >= KH) ? (2 * KH - 2 - hh) : hh;
        const float* __restrict__ rp = xp + (size_t)hh * KW;

        const float4 s0 = *reinterpret_cast<const float4*>(rp + b0);
        const float4 s1 = *reinterpret_cast<const float4*>(rp + w0);
        const float4 s2 = *reinterpret_cast<const float4*>(rp + b2);
        float win[12] = { s0.x, s0.y, s0.z, s0.w,
                          s1.x, s1.y, s1.z, s1.w,
                          s2.x, s2.y, s2.z, s2.w };
        // reflect fixups (register selects, no extra loads)
        win[3] = left ? win[1] : win[3];
        const float f8 = right ? win[6] : win[8];
        const float f9 = right ? win[5] : win[9];
        win[8] = f8; win[9] = f9;

#pragma unroll
        for (int j = 0; j < 5; ++j) {
            if (ki == 2 && j == 2) continue;   // folded into den init
            const float wkv = wsp[ki * 5 + j]; // uniform -> SGPR
            {
                const f32x2 p = {win[2 + j], win[3 + j]};
                const f32x2 d = p - c01;
                const f32x2 t = d * A;
                const f32x2 s = d * t + Cv;    // pk_fma: d^2*A + C  (>0 for |d|<13)
                f32x2 e;
                e.x = __int_as_float((int)s.x);
                e.y = __int_as_float((int)s.y);
                const f32x2 g = e * wkv;
                num01 = num01 + g * d;
                den01 = den01 + g;
            }
            {
                const f32x2 p = {win[4 + j], win[5 + j]};
                const f32x2 d = p - c23;
                const f32x2 t = d * A;
                const f32x2 s = d * t + Cv;
                f32x2 e;
                e.x = __int_as_float((int)s.x);
                e.y = __int_as_float((int)s.y);
                const f32x2 g = e * wkv;
                num23 = num23 + g * d;
                den23 = den23 + g;
            }
        }
    }

    float4 o;
    o.x = cv.x + __fdividef(num01.x, den01.x);
    o.y = cv.y + __fdividef(num01.y, den01.y);
    o.z = cv.z + __fdividef(num23.x, den23.x);
    o.w = cv.w + __fdividef(num23.y, den23.y);
    *reinterpret_cast<float4*>(out + (size_t)plane * KH * KW + (size_t)h * KW + w0) = o;
}

extern "C" void kernel_launch(void* const* d_in, const int* in_sizes, int n_in,
                              void* d_out, int out_size, void* d_ws, size_t ws_size,
                              hipStream_t stream) {
    const float* x   = (const float*)d_in[0];
    const float* wsp = (const float*)d_in[1];
    float* out = (float*)d_out;

    const int planes = out_size / (KH * KW);  // B*C = 12

    dim3 block(64, 4, 1);
    dim3 grid(KW / (64 * TW), KH / 4, planes);
    TrainableFilter_75118978007282_kernel<<<grid, block, 0, stream>>>(x, wsp, out);
}